// Round 10
// baseline (240.719 us; speedup 1.0000x reference)
//
#include <hip/hip_runtime.h>

// GraphConv B=256,N=512,D=6,F=128,MAX_DEG=6.
// R15 post-mortem: barrier-free 8-blk/CU 54%-occ gather STILL 1.48 TB/s ->
// blocks/waves are not the lever. MLP model fits all 10 runs: BW tracks
// outstanding bytes/CU (need ~15KB for 6.3TB/s; convoy=4KB, R15 j-loop
// serialized ~128B/thread). R16 = R15 + (1) branchless gather issuing ALL
// 28 float4 loads per 16-float segment at once (self + 6 nbrs; invalid edge
// -> self addr, weight 0 via fmaf) = ~28KB in flight/wave; (2) XCD swizzle:
// all 8 chunks of a molecule -> same idx%8 (same XCD L2, adjacent dispatch
// slots) -> kill R15's 116MB cross-XCD re-fetch.

typedef short bf16x8 __attribute__((ext_vector_type(8)));
typedef float f32x4  __attribute__((ext_vector_type(4)));
typedef unsigned short ushort_t;
typedef unsigned int uint_t;

constexpr int Nn = 512;
constexpr int Ff = 128;
constexpr int RB = 64;                          // rows per block

// ws: Wt bf16 [6][128][128] ([d][n][k])
constexpr size_t WS_NEEDED = 196608;

__device__ inline ushort_t f2bf(float f) {      // round-to-nearest-even
    uint_t u = __float_as_uint(f);
    return (ushort_t)((u + 0x7FFFu + ((u >> 16) & 1u)) >> 16);
}

__device__ inline bool detect_is64(const int* edges32) {
    // int64 edges: odd dwords are sign-extension words in {0,-1}.
    int probe = edges32[2 * (threadIdx.x & 63) + 1];
    return __any(probe > 0) == 0;
}

// ---------------- k0: W fp32 [d][k][n] -> Wt bf16 [d][n][k] ----------------
__global__ __launch_bounds__(1024)
void k0_wt(const float* __restrict__ W, ushort_t* __restrict__ Wt) {
    __shared__ float w[128 * 133];              // pad 133: conflict-free transpose
    const int d = blockIdx.x;
    const float* src = W + (size_t)d * 16384;
    #pragma unroll
    for (int i = 0; i < 16; i++) {
        int idx = threadIdx.x + i * 1024;       // [k][n] linear, coalesced read
        w[(idx >> 7) * 133 + (idx & 127)] = src[idx];
    }
    __syncthreads();
    ushort_t* dst = Wt + (size_t)d * 16384;
    #pragma unroll
    for (int i = 0; i < 16; i++) {
        int idx = threadIdx.x + i * 1024;       // [n][k] linear, coalesced write
        dst[idx] = f2bf(w[(idx & 127) * 133 + (idx >> 7)]);
    }
}

// ---------------- fused: 64-row chunks, MLP-max register gather -------------
// summed granule g(k0,row,kq) = k0*(RB*4) + row*4 + (kq ^ (row&3)); 16B each.
__global__ __launch_bounds__(256)
void k_fused(const float* __restrict__ atoms,
             const int*   __restrict__ edges32,
             const ushort_t* __restrict__ Wt,
             const float* __restrict__ bias,
             float* __restrict__ out) {
    const int tid  = threadIdx.x;
    // XCD swizzle: chunk w = idx/8 + (idx%8)*256 (grid 2048, bijective).
    // All 8 chunks of molecule m share idx%8 (same XCD) and are dispatched
    // within 8 wgids of each other -> neighbor rows L2-hot, no cross-XCD dup.
    const int wch  = (blockIdx.x >> 3) + (blockIdx.x & 7) * 256;
    const int row0 = wch * RB;                  // flat atom-row base
    const int molbase = row0 & ~(Nn - 1);       // molecule start (RB | Nn)
    const bool is64 = detect_is64(edges32);     // convergent

    __shared__ __attribute__((aligned(16))) ushort_t summed[RB * 128];  // 16384 B
    __shared__ ushort_t nbp[RB * 6];            // 768 B packed nbr ids
    __shared__ ushort_t rlist[RB];              // degree-sorted local rows
    __shared__ int hist[8];

    const int pr = tid >> 2, h = tid & 3;       // row / col-quarter (32 floats)

    // --- phase 0: degrees, ranks, sorted row list (one barrier pair) ---
    if (tid < 8) hist[tid] = 0;
    __syncthreads();
    int deg = 0;
    {
        int e[6];
        const size_t eb = (size_t)(row0 + pr) * 6;
        if (is64) {
            #pragma unroll
            for (int j = 0; j < 6; j++) e[j] = edges32[(eb + j) * 2];
        } else {
            #pragma unroll
            for (int j = 0; j < 6; j++) e[j] = edges32[eb + j];
        }
        #pragma unroll
        for (int j = 0; j < 6; j++) deg += (e[j] >= 0) ? 1 : 0;
        if (deg > 5) deg = 5;                   // spec: deg<=5; guard
        if (h == 0) {
            #pragma unroll
            for (int j = 0; j < 6; j++)
                nbp[pr * 6 + j] = (ushort_t)(e[j] >= 0 ? e[j] : 0xFFFF);
        }
    }
    int rk = 0;
    if (h == 0) rk = atomicAdd(&hist[deg], 1);
    __syncthreads();
    int cnts[6], cbase[6];
    {
        int a = 0;
        #pragma unroll
        for (int d = 0; d < 6; d++) { cnts[d] = hist[d]; cbase[d] = a; a += cnts[d]; }
    }
    if (h == 0) rlist[cbase[deg] + rk] = (ushort_t)pr;
    __syncthreads();

    // --- gather: branchless, all-loads-issued-at-once (MLP ~448B/thread) ---
    const int lr = rlist[pr];                   // my row (sorted order)
    const int selfrow = row0 + lr;
    int nrow[6]; float wgt[6];
    #pragma unroll
    for (int j = 0; j < 6; j++) {
        int e = nbp[lr * 6 + j];
        bool v = (e != 0xFFFF);
        nrow[j] = v ? (molbase + e) : selfrow;  // always-valid address
        wgt[j]  = v ? 1.0f : 0.0f;              // fmaf-predicated
    }

    #pragma unroll
    for (int p = 0; p < 2; p++) {               // two 16-float half-segments
        const int c0 = h * 32 + p * 16;         // col base of this segment
        const float4* sp = (const float4*)(atoms + (size_t)selfrow * Ff + c0);
        float4 acc[4];
        float4 nb0[4], nb1[4], nb2[4], nb3[4], nb4[4], nb5[4];
        const float4* p0 = (const float4*)(atoms + (size_t)nrow[0] * Ff + c0);
        const float4* p1 = (const float4*)(atoms + (size_t)nrow[1] * Ff + c0);
        const float4* p2 = (const float4*)(atoms + (size_t)nrow[2] * Ff + c0);
        const float4* p3 = (const float4*)(atoms + (size_t)nrow[3] * Ff + c0);
        const float4* p4 = (const float4*)(atoms + (size_t)nrow[4] * Ff + c0);
        const float4* p5 = (const float4*)(atoms + (size_t)nrow[5] * Ff + c0);
        #pragma unroll
        for (int q = 0; q < 4; q++) acc[q] = sp[q];     // 28 loads, no deps:
        #pragma unroll
        for (int q = 0; q < 4; q++) nb0[q] = p0[q];
        #pragma unroll
        for (int q = 0; q < 4; q++) nb1[q] = p1[q];
        #pragma unroll
        for (int q = 0; q < 4; q++) nb2[q] = p2[q];
        #pragma unroll
        for (int q = 0; q < 4; q++) nb3[q] = p3[q];
        #pragma unroll
        for (int q = 0; q < 4; q++) nb4[q] = p4[q];
        #pragma unroll
        for (int q = 0; q < 4; q++) nb5[q] = p5[q];
        #pragma unroll
        for (int q = 0; q < 4; q++) {
            acc[q].x = fmaf(nb0[q].x, wgt[0], acc[q].x);
            acc[q].y = fmaf(nb0[q].y, wgt[0], acc[q].y);
            acc[q].z = fmaf(nb0[q].z, wgt[0], acc[q].z);
            acc[q].w = fmaf(nb0[q].w, wgt[0], acc[q].w);
            acc[q].x = fmaf(nb1[q].x, wgt[1], acc[q].x);
            acc[q].y = fmaf(nb1[q].y, wgt[1], acc[q].y);
            acc[q].z = fmaf(nb1[q].z, wgt[1], acc[q].z);
            acc[q].w = fmaf(nb1[q].w, wgt[1], acc[q].w);
            acc[q].x = fmaf(nb2[q].x, wgt[2], acc[q].x);
            acc[q].y = fmaf(nb2[q].y, wgt[2], acc[q].y);
            acc[q].z = fmaf(nb2[q].z, wgt[2], acc[q].z);
            acc[q].w = fmaf(nb2[q].w, wgt[2], acc[q].w);
            acc[q].x = fmaf(nb3[q].x, wgt[3], acc[q].x);
            acc[q].y = fmaf(nb3[q].y, wgt[3], acc[q].y);
            acc[q].z = fmaf(nb3[q].z, wgt[3], acc[q].z);
            acc[q].w = fmaf(nb3[q].w, wgt[3], acc[q].w);
            acc[q].x = fmaf(nb4[q].x, wgt[4], acc[q].x);
            acc[q].y = fmaf(nb4[q].y, wgt[4], acc[q].y);
            acc[q].z = fmaf(nb4[q].z, wgt[4], acc[q].z);
            acc[q].w = fmaf(nb4[q].w, wgt[4], acc[q].w);
            acc[q].x = fmaf(nb5[q].x, wgt[5], acc[q].x);
            acc[q].y = fmaf(nb5[q].y, wgt[5], acc[q].y);
            acc[q].z = fmaf(nb5[q].z, wgt[5], acc[q].z);
            acc[q].w = fmaf(nb5[q].w, wgt[5], acc[q].w);
        }
        // pack 16 f32 -> 2 swizzled granules (k0=h, kq=2p,2p+1)
        #pragma unroll
        for (int u = 0; u < 2; u++) {
            uint4 o;
            o.x = (uint_t)f2bf(acc[2 * u].x)     | ((uint_t)f2bf(acc[2 * u].y) << 16);
            o.y = (uint_t)f2bf(acc[2 * u].z)     | ((uint_t)f2bf(acc[2 * u].w) << 16);
            o.z = (uint_t)f2bf(acc[2 * u + 1].x) | ((uint_t)f2bf(acc[2 * u + 1].y) << 16);
            o.w = (uint_t)f2bf(acc[2 * u + 1].z) | ((uint_t)f2bf(acc[2 * u + 1].w) << 16);
            int g = h * (RB * 4) + lr * 4 + ((2 * p + u) ^ (lr & 3));
            *(uint4*)&summed[g * 8] = o;
        }
    }
    __syncthreads();                            // summed complete

    // --- phase B: flattened MFMA items over the 64 rows ---
    const int lane = tid & 63, wid = tid >> 6;  // 4 waves
    const int kq = lane >> 4, ml = lane & 15;

    int Tp[7];
    {
        int a = 0;
        #pragma unroll
        for (int d = 0; d < 6; d++) { Tp[d] = a; a += ((cnts[d] + 15) >> 4) * 4; }
        Tp[6] = a;
    }
    const int items = Tp[6];

    for (int it = wid; it < items; it += 4) {
        int d = 0;
        #pragma unroll
        for (int dd = 1; dd < 6; dd++) if (it >= Tp[dd]) d = dd;
        const int loc = it - Tp[d];
        const int ti = loc >> 2, ci = loc & 3;  // row-tile, col-pair
        const int cn = cnts[d], cb = cbase[d];

        int lidx = ti * 16 + ml;
        int cl = (lidx < cn) ? lidx : cn - 1;   // clamp; stores masked
        int row = rlist[cb + cl];               // local row
        bf16x8 af[4];                           // A: m=ml, k=kq*8+k0*32
        #pragma unroll
        for (int k0 = 0; k0 < 4; k0++)
            af[k0] = *(const bf16x8*)&summed[(k0 * (RB * 4) + row * 4 + (kq ^ (row & 3))) * 8];
        int orw[4];                             // C/D rows: kq*4+reg
        #pragma unroll
        for (int r = 0; r < 4; r++) {
            int li = ti * 16 + kq * 4 + r;
            orw[r] = (li < cn) ? (int)rlist[cb + li] : -1;
        }
        const ushort_t* wg = Wt + (size_t)d * 16384;
        #pragma unroll
        for (int n2 = 0; n2 < 2; n2++) {
            const int nt = ci * 2 + n2;
            bf16x8 bfr[4];                      // B: n=ml, k=kq*8+k0*32 (global, L2-hot)
            #pragma unroll
            for (int k0 = 0; k0 < 4; k0++)
                bfr[k0] = *(const bf16x8*)&wg[(nt * 16 + ml) * 128 + k0 * 32 + kq * 8];
            f32x4 c = {0.f, 0.f, 0.f, 0.f};
            #pragma unroll
            for (int k0 = 0; k0 < 4; k0++)
                c = __builtin_amdgcn_mfma_f32_16x16x32_bf16(af[k0], bfr[k0], c, 0, 0, 0);
            const int col = nt * 16 + ml;
            const float bc = bias[d * Ff + col];
            #pragma unroll
            for (int r = 0; r < 4; r++) {
                if (orw[r] >= 0) {
                    float v = c[r] + bc;
                    out[(size_t)(row0 + orw[r]) * Ff + col] = v > 0.f ? v : 0.f;
                }
            }
        }
    }
}

// ---------------- fallback (round-1 kernel) if ws too small ----------------
__global__ __launch_bounds__(128, 2)
void graphconv_fallback(const float* __restrict__ atoms,
                        const int* __restrict__ edges_raw,
                        const float* __restrict__ W,
                        const float* __restrict__ bias,
                        float* __restrict__ out) {
    const int tid = threadIdx.x;
    const int d = blockIdx.x % 6;
    const int k = blockIdx.x / 6;
    const int a0 = k * 256;
    __shared__ int eds[256 * 6];
    __shared__ int list[256];
    __shared__ int cnt;
    __shared__ float sv[2][Ff];
    bool is64;
    { int v = edges_raw[2 * (tid & 63) + 1]; is64 = (__ballot(v > 0) == 0ull); }
    if (!is64) { for (int i = tid; i < 256 * 6; i += 128) eds[i] = edges_raw[a0 * 6 + i]; }
    else       { for (int i = tid; i < 256 * 6; i += 128) eds[i] = edges_raw[2 * (a0 * 6 + i)]; }
    if (tid == 0) cnt = 0;
    __syncthreads();
    for (int i = tid; i < 256; i += 128) {
        int deg = 0;
        #pragma unroll
        for (int j = 0; j < 6; j++) deg += (eds[i * 6 + j] != -1) ? 1 : 0;
        if (deg == d) { int p = atomicAdd(&cnt, 1); list[p] = i; }
    }
    float Wreg[Ff];
    { const float* Wd = W + (size_t)d * Ff * Ff;
      #pragma unroll
      for (int f = 0; f < Ff; f++) Wreg[f] = Wd[f * Ff + tid]; }
    const float breg = bias[d * Ff + tid];
    __syncthreads();
    const int n = cnt;
    const float* batch_atoms = atoms + (size_t)(a0 / Nn) * Nn * Ff;
    const int row0 = a0 % Nn;
    for (int ii = 0; ii < n; ii++) {
        const int i = list[ii];
        float s = batch_atoms[(row0 + i) * Ff + tid];
        #pragma unroll
        for (int j = 0; j < 6; j++) {
            int e = eds[i * 6 + j];
            if (e != -1) s += batch_atoms[e * Ff + tid];
        }
        float* buf = sv[ii & 1];
        buf[tid] = s;
        __syncthreads();
        float acc = breg;
        const float4* sv4 = (const float4*)buf;
        #pragma unroll
        for (int fc = 0; fc < Ff / 4; fc++) {
            float4 x = sv4[fc];
            acc = fmaf(x.x, Wreg[4 * fc + 0], acc);
            acc = fmaf(x.y, Wreg[4 * fc + 1], acc);
            acc = fmaf(x.z, Wreg[4 * fc + 2], acc);
            acc = fmaf(x.w, Wreg[4 * fc + 3], acc);
        }
        out[(size_t)(a0 + i) * Ff + tid] = fmaxf(acc, 0.0f);
    }
}

extern "C" void kernel_launch(void* const* d_in, const int* in_sizes, int n_in,
                              void* d_out, int out_size, void* d_ws, size_t ws_size,
                              hipStream_t stream) {
    const float* atoms = (const float*)d_in[0];
    const int*   edges = (const int*)d_in[1];
    const float* W     = (const float*)d_in[2];
    const float* bias  = (const float*)d_in[3];
    float*       outp  = (float*)d_out;

    if (ws_size >= WS_NEEDED) {
        ushort_t* Wt = (ushort_t*)d_ws;
        k0_wt<<<6, 1024, 0, stream>>>(W, Wt);
        k_fused<<<(256 * Nn) / RB, 256, 0, stream>>>(atoms, edges, Wt, bias, outp);
    } else {
        graphconv_fallback<<<3072, 128, 0, stream>>>(atoms, edges, W, bias, outp);
    }
}

// Round 11
// 178.260 us; speedup vs baseline: 1.3504x; 1.3504x over previous
//
#include <hip/hip_runtime.h>

// GraphConv B=256,N=512,D=6,F=128,MAX_DEG=6.
// R16 post-mortem: XCD swizzle fixed FETCH (116->35MB) but MLP gather was
// register-starved (VGPR=48: compiler serialized the 28 loads) + always-6
// reads doubled L2 traffic -> 0.7TB/s. 11-round synthesis: barrier-convoy
// designs pin at 1.5-1.8 TB/s; deep-batched STAGED streaming is the only
// pattern that exceeded it. R17: 2-period structure, ~6 barriers total.
// Block=molecule, 512thr. abuf=[512][64]fp32=128KB (half of K per period),
// XOR-swizzled 16B granules (slot s holds granule s^(row&15)). Per period:
// reg ping-pong staged fill (4xfloat4 batches, deep MLP), 1 barrier, then
// each wave does 5 static tile-slots: gather self+nbrs k-slices from abuf
// (tiles degree-grouped -> j<d wave-uniform; unrolled static per rule #20),
// pack bf16 af, MFMA into persistent acc[5][8] (160 VGPR, lb(512,2)).
// K accumulates across periods; bias+relu+store fused into period 1.

typedef short bf16x8 __attribute__((ext_vector_type(8)));
typedef float f32x4  __attribute__((ext_vector_type(4)));
typedef unsigned short ushort_t;
typedef unsigned int uint_t;

constexpr int Nn = 512;
constexpr int Ff = 128;

// ws: Wt bf16 [6][128][128] ([d][n][k])
constexpr size_t WS_NEEDED = 196608;

__device__ inline ushort_t f2bf(float f) {      // round-to-nearest-even
    uint_t u = __float_as_uint(f);
    return (ushort_t)((u + 0x7FFFu + ((u >> 16) & 1u)) >> 16);
}

__device__ inline bool detect_is64(const int* edges32) {
    // int64 edges: odd dwords are sign-extension words in {0,-1}.
    int probe = edges32[2 * (threadIdx.x & 63) + 1];
    return __any(probe > 0) == 0;
}

// ---------------- k0: W fp32 [d][k][n] -> Wt bf16 [d][n][k] ----------------
__global__ __launch_bounds__(1024)
void k0_wt(const float* __restrict__ W, ushort_t* __restrict__ Wt) {
    __shared__ float w[128 * 133];              // pad 133: conflict-free transpose
    const int d = blockIdx.x;
    const float* src = W + (size_t)d * 16384;
    #pragma unroll
    for (int i = 0; i < 16; i++) {
        int idx = threadIdx.x + i * 1024;       // [k][n] linear, coalesced read
        w[(idx >> 7) * 133 + (idx & 127)] = src[idx];
    }
    __syncthreads();
    ushort_t* dst = Wt + (size_t)d * 16384;
    #pragma unroll
    for (int i = 0; i < 16; i++) {
        int idx = threadIdx.x + i * 1024;       // [n][k] linear, coalesced write
        dst[idx] = f2bf(w[(idx & 127) * 133 + (idx >> 7)]);
    }
}

// ---------------- fused: molecule/block, 2 periods, 6 barriers -------------
__global__ __launch_bounds__(512, 2)
void k_fused(const float* __restrict__ atoms,
             const int*   __restrict__ edges32,
             const ushort_t* __restrict__ Wt,
             const float* __restrict__ bias,
             float* __restrict__ out) {
    const int tid = threadIdx.x;
    const int mol = blockIdx.x;
    const bool is64 = detect_is64(edges32);     // convergent

    __shared__ __attribute__((aligned(16))) float abuf[Nn * 64];   // 131072 B
    __shared__ uint_t   nbp3[Nn * 3];           // 6144 B: packed nbr ids (2 per u32)
    __shared__ ushort_t rlist[Nn];              // 1024 B: rows grouped by degree
    __shared__ int hist[8];
    float4* abuf4 = (float4*)abuf;              // 8192 granules of 16B

    // --- phase 0: edges -> nbp3, degree ranks -> rlist ---
    if (tid < 8) hist[tid] = 0;
    __syncthreads();
    int deg = 0;
    {
        int e[6];
        if (is64) {                             // 48B/row, 16B-aligned
            const uint4* ep = (const uint4*)(edges32 + ((size_t)mol * (Nn * 6) + (size_t)tid * 6) * 2);
            uint4 q0 = ep[0], q1 = ep[1], q2 = ep[2];
            e[0] = (int)q0.x; e[1] = (int)q0.z;
            e[2] = (int)q1.x; e[3] = (int)q1.z;
            e[4] = (int)q2.x; e[5] = (int)q2.z;
        } else {                                // 24B/row, 8B-aligned
            const uint2* ep = (const uint2*)(edges32 + (size_t)mol * (Nn * 6) + (size_t)tid * 6);
            uint2 q0 = ep[0], q1 = ep[1], q2 = ep[2];
            e[0] = (int)q0.x; e[1] = (int)q0.y;
            e[2] = (int)q1.x; e[3] = (int)q1.y;
            e[4] = (int)q2.x; e[5] = (int)q2.y;
        }
        #pragma unroll
        for (int j = 0; j < 6; j++) deg += (e[j] >= 0) ? 1 : 0;
        if (deg > 5) deg = 5;                   // spec: deg<=5; guard
        nbp3[tid * 3 + 0] = ((uint_t)e[0] & 0xFFFFu) | (((uint_t)e[1] & 0xFFFFu) << 16);
        nbp3[tid * 3 + 1] = ((uint_t)e[2] & 0xFFFFu) | (((uint_t)e[3] & 0xFFFFu) << 16);
        nbp3[tid * 3 + 2] = ((uint_t)e[4] & 0xFFFFu) | (((uint_t)e[5] & 0xFFFFu) << 16);
    }
    int rk = atomicAdd(&hist[deg], 1);
    __syncthreads();
    int cnts[6], cbase[6];
    {
        int a = 0;
        #pragma unroll
        for (int d = 0; d < 6; d++) { cnts[d] = hist[d]; cbase[d] = a; a += cnts[d]; }
    }
    rlist[cbase[deg] + rk] = (ushort_t)tid;     // visible after next barrier

    const int lane = tid & 63, wid = tid >> 6;  // 8 waves
    const int kq = lane >> 4, ml = lane & 15;
    const float* gA = atoms + (size_t)mol * (Nn * Ff);

    f32x4 acc[5][8];                            // 160 VGPR: 5 tile-slots x 8 nt
    #pragma unroll
    for (int q = 0; q < 5; q++)
        #pragma unroll
        for (int n = 0; n < 8; n++) acc[q][n] = (f32x4){0.f, 0.f, 0.f, 0.f};

    // stage coords: thread covers granules L = i*512+tid, i=0..15.
    // row(L)=L>>4 = i*32 + (tid>>4); slot s = tid&15; LDS slot s of row r
    // holds global granule s^(r&15)  -> reader uses abuf4[r*16 + (g^(r&15))].
    const int srow4 = tid >> 4;                 // 0..31; row&15 = srow4&15 (const)
    const int sg = (tid & 15) ^ (srow4 & 15);   // my global granule (const)

    for (int p = 0; p < 2; p++) {
        __syncthreads();                        // abuf free (phase0 / prev gathers done)
        // ---- stage abuf: 16 granules/thread, ping-pong batches of 4 ----
        {
            const float* gp = gA + p * 64 + sg * 4;
            float4 ra[4], rb[4];
            #pragma unroll
            for (int u = 0; u < 4; u++)
                ra[u] = *(const float4*)(gp + (size_t)(u * 32 + srow4) * Ff);
            #pragma unroll
            for (int b = 0; b < 4; b++) {
                if (b < 3) {
                    #pragma unroll
                    for (int u = 0; u < 4; u++)
                        rb[u] = *(const float4*)(gp + (size_t)(((b + 1) * 4 + u) * 32 + srow4) * Ff);
                }
                #pragma unroll
                for (int u = 0; u < 4; u++)
                    abuf4[(b * 4 + u) * 512 + tid] = ra[u];
                #pragma unroll
                for (int u = 0; u < 4; u++) ra[u] = rb[u];
            }
        }
        __syncthreads();                        // abuf(period p) ready

        // ---- compute: 5 static tile-slots per wave ----
        #pragma unroll
        for (int q = 0; q < 5; q++) {
            const int t = wid + q * 8;          // tile id 0..39
            int d = -1, ti = 0;
            {
                int a = 0;
                #pragma unroll
                for (int dd = 0; dd < 6; dd++) {
                    int tl = (cnts[dd] + 15) >> 4;
                    if (d < 0 && t < a + tl) { d = dd; ti = t - a; }
                    a += tl;
                }
            }
            if (d < 0) continue;                // dummy slot (wave-uniform)
            const int cn = cnts[d], cb = cbase[d];

            const int lidx = ti * 16 + ml;
            const int cl = (lidx < cn) ? lidx : cn - 1;   // clamp; stores masked
            const int R = rlist[cb + cl];
            const uint_t w0 = nbp3[R * 3], w1 = nbp3[R * 3 + 1], w2 = nbp3[R * 3 + 2];
            const int er[6] = { (int)(w0 & 0xFFFFu), (int)(w0 >> 16),
                                (int)(w1 & 0xFFFFu), (int)(w1 >> 16),
                                (int)(w2 & 0xFFFFu), (int)(w2 >> 16) };

            #pragma unroll
            for (int kl = 0; kl < 2; kl++) {    // two k0 chunks this period
                const int g0 = kl * 8 + kq * 2;
                float4 s0 = abuf4[R * 16 + (g0 ^ (R & 15))];
                float4 s1 = abuf4[R * 16 + ((g0 + 1) ^ (R & 15))];
                #pragma unroll
                for (int j = 0; j < 6; j++) {   // j static (rule #20); bound uniform
                    if (j < d) {                // tile degree == d for all lanes
                        const int e = er[j];
                        float4 v0 = abuf4[e * 16 + (g0 ^ (e & 15))];
                        float4 v1 = abuf4[e * 16 + ((g0 + 1) ^ (e & 15))];
                        s0.x += v0.x; s0.y += v0.y; s0.z += v0.z; s0.w += v0.w;
                        s1.x += v1.x; s1.y += v1.y; s1.z += v1.z; s1.w += v1.w;
                    }
                }
                uint4 o;
                o.x = (uint_t)f2bf(s0.x) | ((uint_t)f2bf(s0.y) << 16);
                o.y = (uint_t)f2bf(s0.z) | ((uint_t)f2bf(s0.w) << 16);
                o.z = (uint_t)f2bf(s1.x) | ((uint_t)f2bf(s1.y) << 16);
                o.w = (uint_t)f2bf(s1.z) | ((uint_t)f2bf(s1.w) << 16);
                const bf16x8 af = *(const bf16x8*)&o;    // A[m=ml][k0*32+kq*8..+8]
                const int k0 = p * 2 + kl;
                const ushort_t* wg = Wt + (size_t)d * 16384 + k0 * 32 + kq * 8;
                #pragma unroll
                for (int nt = 0; nt < 8; nt++) {
                    const bf16x8 bfr = *(const bf16x8*)&wg[(nt * 16 + ml) * 128];
                    acc[q][nt] = __builtin_amdgcn_mfma_f32_16x16x32_bf16(af, bfr, acc[q][nt], 0, 0, 0);
                }
            }

            if (p == 1) {                       // K complete: epilogue fused
                int orw[4];
                #pragma unroll
                for (int r = 0; r < 4; r++) {
                    int li = ti * 16 + kq * 4 + r;
                    orw[r] = (li < cn) ? (int)rlist[cb + li] : -1;
                }
                #pragma unroll
                for (int nt = 0; nt < 8; nt++) {
                    const int col = nt * 16 + ml;
                    const float bc = bias[d * Ff + col];
                    #pragma unroll
                    for (int r = 0; r < 4; r++) {
                        if (orw[r] >= 0) {
                            float v = acc[q][nt][r] + bc;
                            out[((size_t)mol * Nn + orw[r]) * Ff + col] = v > 0.f ? v : 0.f;
                        }
                    }
                }
            }
        }
    }
}

// ---------------- fallback (round-1 kernel) if ws too small ----------------
__global__ __launch_bounds__(128, 2)
void graphconv_fallback(const float* __restrict__ atoms,
                        const int* __restrict__ edges_raw,
                        const float* __restrict__ W,
                        const float* __restrict__ bias,
                        float* __restrict__ out) {
    const int tid = threadIdx.x;
    const int d = blockIdx.x % 6;
    const int k = blockIdx.x / 6;
    const int a0 = k * 256;
    __shared__ int eds[256 * 6];
    __shared__ int list[256];
    __shared__ int cnt;
    __shared__ float sv[2][Ff];
    bool is64;
    { int v = edges_raw[2 * (tid & 63) + 1]; is64 = (__ballot(v > 0) == 0ull); }
    if (!is64) { for (int i = tid; i < 256 * 6; i += 128) eds[i] = edges_raw[a0 * 6 + i]; }
    else       { for (int i = tid; i < 256 * 6; i += 128) eds[i] = edges_raw[2 * (a0 * 6 + i)]; }
    if (tid == 0) cnt = 0;
    __syncthreads();
    for (int i = tid; i < 256; i += 128) {
        int deg = 0;
        #pragma unroll
        for (int j = 0; j < 6; j++) deg += (eds[i * 6 + j] != -1) ? 1 : 0;
        if (deg == d) { int p = atomicAdd(&cnt, 1); list[p] = i; }
    }
    float Wreg[Ff];
    { const float* Wd = W + (size_t)d * Ff * Ff;
      #pragma unroll
      for (int f = 0; f < Ff; f++) Wreg[f] = Wd[f * Ff + tid]; }
    const float breg = bias[d * Ff + tid];
    __syncthreads();
    const int n = cnt;
    const float* batch_atoms = atoms + (size_t)(a0 / Nn) * Nn * Ff;
    const int row0 = a0 % Nn;
    for (int ii = 0; ii < n; ii++) {
        const int i = list[ii];
        float s = batch_atoms[(row0 + i) * Ff + tid];
        #pragma unroll
        for (int j = 0; j < 6; j++) {
            int e = eds[i * 6 + j];
            if (e != -1) s += batch_atoms[e * Ff + tid];
        }
        float* buf = sv[ii & 1];
        buf[tid] = s;
        __syncthreads();
        float acc = breg;
        const float4* sv4 = (const float4*)buf;
        #pragma unroll
        for (int fc = 0; fc < Ff / 4; fc++) {
            float4 x = sv4[fc];
            acc = fmaf(x.x, Wreg[4 * fc + 0], acc);
            acc = fmaf(x.y, Wreg[4 * fc + 1], acc);
            acc = fmaf(x.z, Wreg[4 * fc + 2], acc);
            acc = fmaf(x.w, Wreg[4 * fc + 3], acc);
        }
        out[(size_t)(a0 + i) * Ff + tid] = fmaxf(acc, 0.0f);
    }
}

extern "C" void kernel_launch(void* const* d_in, const int* in_sizes, int n_in,
                              void* d_out, int out_size, void* d_ws, size_t ws_size,
                              hipStream_t stream) {
    const float* atoms = (const float*)d_in[0];
    const int*   edges = (const int*)d_in[1];
    const float* W     = (const float*)d_in[2];
    const float* bias  = (const float*)d_in[3];
    float*       outp  = (float*)d_out;

    if (ws_size >= WS_NEEDED) {
        ushort_t* Wt = (ushort_t*)d_ws;
        k0_wt<<<6, 1024, 0, stream>>>(W, Wt);
        k_fused<<<256, 512, 0, stream>>>(atoms, edges, Wt, bias, outp);
    } else {
        graphconv_fallback<<<3072, 128, 0, stream>>>(atoms, edges, W, bias, outp);
    }
}